// Round 1
// baseline (2667.125 us; speedup 1.0000x reference)
//
#include <hip/hip_runtime.h>

#define NF 128
#define EPS 1e-5f
#define SLOPE 0.2f

// ---------------- CSR build ----------------

__global__ void k_init_counts(int* counts, int n) {
  int i = blockIdx.x * 256 + threadIdx.x;
  if (i < n) counts[i] = 1;  // self-loop
}

__global__ void k_count(const int* __restrict__ dst, int* __restrict__ counts, int e) {
  int i = blockIdx.x * 256 + threadIdx.x;
  if (i < e) atomicAdd(&counts[dst[i]], 1);
}

__global__ void k_scan_part(const int* __restrict__ counts, int* __restrict__ partials, int n) {
  __shared__ int sd[256];
  int base = blockIdx.x * 2048;
  int sum = 0;
  for (int i = threadIdx.x; i < 2048; i += 256) {
    int idx = base + i;
    sum += (idx < n) ? counts[idx] : 0;
  }
  sd[threadIdx.x] = sum;
  __syncthreads();
  for (int s = 128; s > 0; s >>= 1) {
    if (threadIdx.x < s) sd[threadIdx.x] += sd[threadIdx.x + s];
    __syncthreads();
  }
  if (threadIdx.x == 0) partials[blockIdx.x] = sd[0];
}

__global__ void k_scan_mid(int* partials, int nb) {
  if (threadIdx.x == 0 && blockIdx.x == 0) {
    int acc = 0;
    for (int b = 0; b < nb; b++) { int v = partials[b]; partials[b] = acc; acc += v; }
  }
}

__global__ void k_scan_final(const int* __restrict__ counts, const int* __restrict__ partials,
                             int* __restrict__ offsets, int n) {
  __shared__ int sd[256];
  int t = threadIdx.x;
  int base = blockIdx.x * 2048;
  int local[8];
  int sum = 0;
#pragma unroll
  for (int j = 0; j < 8; j++) {
    int idx = base + t * 8 + j;
    int v = (idx < n) ? counts[idx] : 0;
    local[j] = sum;
    sum += v;
  }
  sd[t] = sum;
  __syncthreads();
  for (int st = 1; st < 256; st <<= 1) {
    int v = 0;
    if (t >= st) v = sd[t - st];
    __syncthreads();
    if (t >= st) sd[t] += v;
    __syncthreads();
  }
  int tb = partials[blockIdx.x] + (t > 0 ? sd[t - 1] : 0);
#pragma unroll
  for (int j = 0; j < 8; j++) {
    int idx = base + t * 8 + j;
    if (idx < n) offsets[idx] = tb + local[j];
  }
}

__global__ void k_selfloop(int* __restrict__ offsets, int* __restrict__ cursor,
                           int* __restrict__ csr, int n, int total) {
  int i = blockIdx.x * 256 + threadIdx.x;
  if (i < n) {
    int o = offsets[i];
    csr[o] = i;          // self-loop first in each segment
    cursor[i] = o + 1;
  }
  if (i == 0) offsets[n] = total;
}

__global__ void k_fill(const int* __restrict__ src, const int* __restrict__ dst,
                       int* __restrict__ cursor, int* __restrict__ csr, int e) {
  int i = blockIdx.x * 256 + threadIdx.x;
  if (i < e) {
    int pos = atomicAdd(&cursor[dst[i]], 1);
    csr[pos] = src[i];
  }
}

// ---------------- GEMM: C[n x 128] = A[n x 128] @ W[128 x 128] (+bias) ----------------
// block: 512 threads, tile 128 rows x 128 cols, K=128 in one shot.

__global__ __launch_bounds__(512) void k_gemm128(const float* __restrict__ A,
                                                 const float* __restrict__ W,
                                                 const float* __restrict__ bias,
                                                 float* __restrict__ C, int n, int has_bias) {
  __shared__ float xs[128][132];  // padded: bank-safe float4 reads over k
  __shared__ float wt[128][128];  // natural [k][c]
  int row0 = blockIdx.x * 128;
  int t = threadIdx.x;
  for (int i = t; i < 128 * 128; i += 512) wt[i >> 7][i & 127] = W[i];
  for (int i = t; i < 128 * 128; i += 512) {
    int r = i >> 7, c = i & 127;
    int gr = row0 + r;
    xs[r][c] = (gr < n) ? A[(size_t)gr * NF + c] : 0.0f;
  }
  __syncthreads();
  int tx = t & 15;   // cols c = tx + 16*j, j=0..7  (conflict-free wt reads)
  int ty = t >> 4;   // rows r = ty*4 + i, i=0..3
  float acc[4][8] = {};
  for (int k = 0; k < 128; k += 4) {
    float4 xv[4];
#pragma unroll
    for (int i2 = 0; i2 < 4; i2++) xv[i2] = *(const float4*)&xs[ty * 4 + i2][k];
#pragma unroll
    for (int kk = 0; kk < 4; kk++) {
      float wv[8];
#pragma unroll
      for (int j = 0; j < 8; j++) wv[j] = wt[k + kk][tx + 16 * j];
#pragma unroll
      for (int i2 = 0; i2 < 4; i2++) {
        float xvv = ((const float*)&xv[i2])[kk];
#pragma unroll
        for (int j = 0; j < 8; j++) acc[i2][j] += xvv * wv[j];
      }
    }
  }
#pragma unroll
  for (int i2 = 0; i2 < 4; i2++) {
    int gr = row0 + ty * 4 + i2;
    if (gr < n) {
#pragma unroll
      for (int j = 0; j < 8; j++) {
        int c = tx + 16 * j;
        float v = acc[i2][j];
        if (has_bias) v += bias[c];
        C[(size_t)gr * NF + c] = v;
      }
    }
  }
}

// ---------------- s = h@a_src, d = h@a_dst (wave per row) ----------------

__global__ void k_sd(const float* __restrict__ h, const float* __restrict__ asrc,
                     const float* __restrict__ adst, float* __restrict__ s,
                     float* __restrict__ d, int n) {
  int row = blockIdx.x * 4 + (threadIdx.x >> 6);
  int lane = threadIdx.x & 63;
  if (row >= n) return;
  float2 hv = *(const float2*)&h[(size_t)row * NF + lane * 2];
  float svv = hv.x * asrc[lane * 2] + hv.y * asrc[lane * 2 + 1];
  float dvv = hv.x * adst[lane * 2] + hv.y * adst[lane * 2 + 1];
#pragma unroll
  for (int m = 32; m > 0; m >>= 1) {
    svv += __shfl_xor(svv, m);
    dvv += __shfl_xor(dvv, m);
  }
  if (lane == 0) { s[row] = svv; d[row] = dvv; }
}

// ---------------- per-edge softmax alpha (wave per dst node) ----------------

__global__ void k_alpha(const float* __restrict__ s, const float* __restrict__ d,
                        const int* __restrict__ offs, const int* __restrict__ csr,
                        float* __restrict__ alpha, int n) {
  int node = blockIdx.x * 4 + (threadIdx.x >> 6);
  int lane = threadIdx.x & 63;
  if (node >= n) return;
  int o0 = offs[node], o1 = offs[node + 1];
  float di = d[node];
  float m = -1e30f;
  for (int j = o0 + lane; j < o1; j += 64) {
    float e = s[csr[j]] + di;
    e = e >= 0.f ? e : SLOPE * e;
    m = fmaxf(m, e);
  }
#pragma unroll
  for (int k = 32; k > 0; k >>= 1) m = fmaxf(m, __shfl_xor(m, k));
  float z = 0.f;
  for (int j = o0 + lane; j < o1; j += 64) {
    float e = s[csr[j]] + di;
    e = e >= 0.f ? e : SLOPE * e;
    z += __expf(e - m);
  }
#pragma unroll
  for (int k = 32; k > 0; k >>= 1) z += __shfl_xor(z, k);
  float inv = 1.0f / z;
  for (int j = o0 + lane; j < o1; j += 64) {
    float e = s[csr[j]] + di;
    e = e >= 0.f ? e : SLOPE * e;
    alpha[j] = __expf(e - m) * inv;
  }
}

// ---------------- weighted gather: agg[i] = sum_j alpha_j * h_lin[src_j] + b ----------------
// wave per node, each lane owns 2 features (float2), unroll edges by 2.

__global__ void k_gather(const float* __restrict__ hlin, const float* __restrict__ alpha,
                         const int* __restrict__ offs, const int* __restrict__ csr,
                         const float* __restrict__ bias, float* __restrict__ out, int n) {
  int node = blockIdx.x * 4 + (threadIdx.x >> 6);
  int lane = threadIdx.x & 63;
  if (node >= n) return;
  int o0 = offs[node], o1 = offs[node + 1];
  float2 acc;
  acc.x = bias[lane * 2];
  acc.y = bias[lane * 2 + 1];
  int j = o0;
  for (; j + 1 < o1; j += 2) {
    int s0 = csr[j], s1 = csr[j + 1];
    float a0 = alpha[j], a1 = alpha[j + 1];
    float2 v0 = *(const float2*)&hlin[(size_t)s0 * NF + lane * 2];
    float2 v1 = *(const float2*)&hlin[(size_t)s1 * NF + lane * 2];
    acc.x += a0 * v0.x + a1 * v1.x;
    acc.y += a0 * v0.y + a1 * v1.y;
  }
  if (j < o1) {
    int s0 = csr[j];
    float a0 = alpha[j];
    float2 v0 = *(const float2*)&hlin[(size_t)s0 * NF + lane * 2];
    acc.x += a0 * v0.x;
    acc.y += a0 * v0.y;
  }
  *(float2*)&out[(size_t)node * NF + lane * 2] = acc;
}

// ---------------- BN stats (column sums) + finalize + apply ----------------

__global__ void k_bnstats(const float* __restrict__ x, float* __restrict__ stats, int n) {
  __shared__ float ls[256], lss[256];
  int col = threadIdx.x & 127;
  int half = threadIdx.x >> 7;
  float s = 0.f, ss = 0.f;
  for (int r = blockIdx.x * 2 + half; r < n; r += gridDim.x * 2) {
    float v = x[(size_t)r * NF + col];
    s += v;
    ss += v * v;
  }
  ls[threadIdx.x] = s;
  lss[threadIdx.x] = ss;
  __syncthreads();
  if (half == 0) {
    s += ls[col + 128];
    ss += lss[col + 128];
    atomicAdd(&stats[col], s);
    atomicAdd(&stats[NF + col], ss);
  }
}

__global__ void k_bnfinal(const float* __restrict__ stats, const float* __restrict__ gamma,
                          const float* __restrict__ beta, float* __restrict__ scsh, float ninv) {
  int c = threadIdx.x;
  float mu = stats[c] * ninv;
  float var = stats[NF + c] * ninv - mu * mu;
  float sc = gamma[c] * rsqrtf(var + EPS);
  scsh[c] = sc;
  scsh[NF + c] = beta[c] - mu * sc;
}

// relu_res=1: out = relu(bn(agg)) + out (residual, in-place on h_cur)
// relu_res=0: out = bn(agg)          (out may alias agg)
__global__ void k_apply(float* outp, const float* agg, const float* __restrict__ scsh,
                        int relu_res, size_t total) {
  for (size_t i = blockIdx.x * (size_t)256 + threadIdx.x; i < total;
       i += (size_t)gridDim.x * 256) {
    int c = (int)(i & (NF - 1));
    float v = agg[i] * scsh[c] + scsh[NF + c];
    if (relu_res) v = fmaxf(v, 0.f) + outp[i];
    outp[i] = v;
  }
}

// ---------------- launcher ----------------

extern "C" void kernel_launch(void* const* d_in, const int* in_sizes, int n_in,
                              void* d_out, int out_size, void* d_ws, size_t ws_size,
                              hipStream_t stream) {
  (void)n_in; (void)out_size; (void)ws_size;
  const float* x     = (const float*)d_in[0];
  const int*   ei    = (const int*)d_in[1];
  const float* W0    = (const float*)d_in[2];
  const float* asrc0 = (const float*)d_in[3];
  const float* adst0 = (const float*)d_in[4];
  const float* b0    = (const float*)d_in[5];
  const float* Wm    = (const float*)d_in[6];
  const float* asrcm = (const float*)d_in[7];
  const float* adstm = (const float*)d_in[8];
  const float* bm    = (const float*)d_in[9];
  const float* W5    = (const float*)d_in[10];
  const float* asrc5 = (const float*)d_in[11];
  const float* adst5 = (const float*)d_in[12];
  const float* b5    = (const float*)d_in[13];
  const float* gammas= (const float*)d_in[14];
  const float* betas = (const float*)d_in[15];
  const float* Wr    = (const float*)d_in[16];
  const float* br    = (const float*)d_in[17];
  const float* Wo    = (const float*)d_in[18];
  const float* bo    = (const float*)d_in[19];

  const int n = in_sizes[0] / NF;
  const int e = in_sizes[1] / 2;
  const int tot = e + n;
  const int* srcp = ei;
  const int* dstp = ei + e;

  char* w = (char*)d_ws;
  auto carve = [&](size_t bytes) {
    char* p = w;
    w += (bytes + 255) & ~(size_t)255;
    return p;
  };
  float* h_lin   = (float*)carve((size_t)n * NF * 4);
  float* agg     = (float*)carve((size_t)n * NF * 4);
  float* h_cur   = (float*)carve((size_t)n * NF * 4);
  float* sv      = (float*)carve((size_t)n * 4);
  float* dv      = (float*)carve((size_t)n * 4);
  float* alpha   = (float*)carve((size_t)tot * 4);
  int*   csr     = (int*)carve((size_t)tot * 4);
  int*   offsets = (int*)carve((size_t)(n + 1) * 4);
  int*   counts  = (int*)carve((size_t)n * 4);  // reused as cursor
  int*   partials= (int*)carve(64 * 4);
  float* stats   = (float*)carve(256 * 4);
  float* scsh    = (float*)carve(256 * 4);

  int nb = (n + 2047) / 2048;

  // CSR build (dst-sorted; self-loop first per segment)
  k_init_counts<<<(n + 255) / 256, 256, 0, stream>>>(counts, n);
  k_count<<<(e + 255) / 256, 256, 0, stream>>>(dstp, counts, e);
  k_scan_part<<<nb, 256, 0, stream>>>(counts, partials, n);
  k_scan_mid<<<1, 64, 0, stream>>>(partials, nb);
  k_scan_final<<<nb, 256, 0, stream>>>(counts, partials, offsets, n);
  k_selfloop<<<(n + 255) / 256, 256, 0, stream>>>(offsets, counts, csr, n, tot);
  k_fill<<<(e + 255) / 256, 256, 0, stream>>>(srcp, dstp, counts, csr, e);

  int gemm_grid = (n + 127) / 128;
  size_t total_el = (size_t)n * NF;

  // residual = x @ Wr + br
  k_gemm128<<<gemm_grid, 512, 0, stream>>>(x, Wr, br, h_cur, n, 1);

  for (int L = 0; L < 6; L++) {
    const float *Wl, *als, *ald, *bl;
    if (L == 0)      { Wl = W0; als = asrc0; ald = adst0; bl = b0; }
    else if (L <= 4) { Wl = Wm + (size_t)(L - 1) * NF * NF; als = asrcm + (L - 1) * NF;
                       ald = adstm + (L - 1) * NF; bl = bm + (L - 1) * NF; }
    else             { Wl = W5; als = asrc5; ald = adst5; bl = b5; }
    const float* hin = (L == 0) ? x : h_cur;

    k_gemm128<<<gemm_grid, 512, 0, stream>>>(hin, Wl, nullptr, h_lin, n, 0);
    k_sd<<<(n + 3) / 4, 256, 0, stream>>>(h_lin, als, ald, sv, dv, n);
    k_alpha<<<(n + 3) / 4, 256, 0, stream>>>(sv, dv, offsets, csr, alpha, n);
    k_gather<<<(n + 3) / 4, 256, 0, stream>>>(h_lin, alpha, offsets, csr, bl, agg, n);

    hipMemsetAsync(stats, 0, 256 * 4, stream);
    k_bnstats<<<1024, 256, 0, stream>>>(agg, stats, n);
    k_bnfinal<<<1, 128, 0, stream>>>(stats, gammas + L * NF, betas + L * NF, scsh, 1.0f / n);

    if (L < 5) {
      k_apply<<<2048, 256, 0, stream>>>(h_cur, agg, scsh, 1, total_el);
    } else {
      k_apply<<<2048, 256, 0, stream>>>(agg, agg, scsh, 0, total_el);
      k_gemm128<<<gemm_grid, 512, 0, stream>>>(agg, Wo, bo, (float*)d_out, n, 1);
    }
  }
}

// Round 2
// 1335.806 us; speedup vs baseline: 1.9966x; 1.9966x over previous
//
#include <hip/hip_runtime.h>

#define NF 128
#define EPS 1e-5f
#define SLOPE 0.2f

typedef __attribute__((ext_vector_type(8))) short bf16x8;
typedef __attribute__((ext_vector_type(4))) float f32x4;

static __device__ __forceinline__ unsigned short f2bf(float f) {
  unsigned int u = __builtin_bit_cast(unsigned int, f);
  u += 0x7fffu + ((u >> 16) & 1u);
  return (unsigned short)(u >> 16);
}

// ---------------- CSR build ----------------

__global__ void k_init_counts(int* counts, int n) {
  int i = blockIdx.x * 256 + threadIdx.x;
  if (i < n) counts[i] = 1;  // self-loop
}

__global__ void k_count(const int* __restrict__ dst, int* __restrict__ counts, int e) {
  int i = blockIdx.x * 256 + threadIdx.x;
  if (i < e) atomicAdd(&counts[dst[i]], 1);
}

__global__ void k_scan_part(const int* __restrict__ counts, int* __restrict__ partials, int n) {
  __shared__ int sd[256];
  int base = blockIdx.x * 2048;
  int sum = 0;
  for (int i = threadIdx.x; i < 2048; i += 256) {
    int idx = base + i;
    sum += (idx < n) ? counts[idx] : 0;
  }
  sd[threadIdx.x] = sum;
  __syncthreads();
  for (int s = 128; s > 0; s >>= 1) {
    if (threadIdx.x < s) sd[threadIdx.x] += sd[threadIdx.x + s];
    __syncthreads();
  }
  if (threadIdx.x == 0) partials[blockIdx.x] = sd[0];
}

__global__ void k_scan_mid(int* partials, int nb) {
  if (threadIdx.x == 0 && blockIdx.x == 0) {
    int acc = 0;
    for (int b = 0; b < nb; b++) { int v = partials[b]; partials[b] = acc; acc += v; }
  }
}

__global__ void k_scan_final(const int* __restrict__ counts, const int* __restrict__ partials,
                             int* __restrict__ offsets, int n) {
  __shared__ int sd[256];
  int t = threadIdx.x;
  int base = blockIdx.x * 2048;
  int local[8];
  int sum = 0;
#pragma unroll
  for (int j = 0; j < 8; j++) {
    int idx = base + t * 8 + j;
    int v = (idx < n) ? counts[idx] : 0;
    local[j] = sum;
    sum += v;
  }
  sd[t] = sum;
  __syncthreads();
  for (int st = 1; st < 256; st <<= 1) {
    int v = 0;
    if (t >= st) v = sd[t - st];
    __syncthreads();
    if (t >= st) sd[t] += v;
    __syncthreads();
  }
  int tb = partials[blockIdx.x] + (t > 0 ? sd[t - 1] : 0);
#pragma unroll
  for (int j = 0; j < 8; j++) {
    int idx = base + t * 8 + j;
    if (idx < n) offsets[idx] = tb + local[j];
  }
}

__global__ void k_selfloop(int* __restrict__ offsets, int* __restrict__ cursor,
                           int* __restrict__ csr, int n, int total) {
  int i = blockIdx.x * 256 + threadIdx.x;
  if (i < n) {
    int o = offsets[i];
    csr[o] = i;          // self-loop first in each segment
    cursor[i] = o + 1;
  }
  if (i == 0) offsets[n] = total;
}

__global__ void k_fill(const int* __restrict__ src, const int* __restrict__ dst,
                       int* __restrict__ cursor, int* __restrict__ csr, int e) {
  int i = blockIdx.x * 256 + threadIdx.x;
  if (i < e) {
    int pos = atomicAdd(&cursor[dst[i]], 1);
    csr[pos] = src[i];
  }
}

// ---------------- converts ----------------

// x (f32, n rows) -> bf16 padded to np rows (pad = 0)
__global__ void k_f32_to_bf16(const float* __restrict__ x, unsigned short* __restrict__ o,
                              int n, int np) {
  int idx = blockIdx.x * 256 + threadIdx.x;
  if (idx >= np * NF) return;
  int row = idx >> 7;
  o[idx] = (row < n) ? f2bf(x[idx]) : (unsigned short)0;
}

// all 8 weight matrices -> bf16 transposed Wt[mat][ncol][k]
__global__ void k_wt(const float* __restrict__ W0, const float* __restrict__ Wm,
                     const float* __restrict__ W5, const float* __restrict__ Wr,
                     const float* __restrict__ Wo, unsigned short* __restrict__ Wt) {
  int idx = blockIdx.x * 256 + threadIdx.x;  // 8 * 16384
  if (idx >= 8 * NF * NF) return;
  int mat = idx >> 14;
  int rem = idx & 16383;
  int r = rem >> 7;   // output col (n)
  int k = rem & 127;  // k
  const float* W = (mat == 0) ? W0
                 : (mat <= 4) ? Wm + (size_t)(mat - 1) * NF * NF
                 : (mat == 5) ? W5
                 : (mat == 6) ? Wr : Wo;
  Wt[idx] = f2bf(W[k * NF + r]);
}

// ---------------- MFMA GEMM: C[np x 128] = A_bf16[np x 128] @ W[128 x 128] ----------------
// 256 threads = 4 waves; wave w owns rows [blk*128 + w*32, +32). No LDS.
// MODE 0: write C bf16 to Cb (unguarded, padded) + fused s/d row-dots.
// MODE 1: write C f32 + bias to Cf (guarded row < n).

template <int MODE>
__global__ __launch_bounds__(256) void k_gemm_mfma(
    const unsigned short* __restrict__ A, const unsigned short* __restrict__ Wt,
    const float* __restrict__ asrc, const float* __restrict__ adst,
    const float* __restrict__ bias, unsigned short* __restrict__ Cb,
    float* __restrict__ Cf, float* __restrict__ sv, float* __restrict__ dv, int n) {
  int w = threadIdx.x >> 6;
  int l = threadIdx.x & 63;
  int lr = l & 15, lh = l >> 4;
  int row0 = blockIdx.x * 128 + w * 32;

  // A fragments: m in {0,1}, kk in 0..3
  const unsigned short* Ab = A + (size_t)(row0 + lr) * NF + lh * 8;
  bf16x8 af[2][4];
#pragma unroll
  for (int m = 0; m < 2; m++)
#pragma unroll
    for (int kk = 0; kk < 4; kk++)
      af[m][kk] = *(const bf16x8*)(Ab + m * 16 * NF + kk * 32);

  f32x4 acc[2][8];
#pragma unroll
  for (int m = 0; m < 2; m++)
#pragma unroll
    for (int nn = 0; nn < 8; nn++) acc[m][nn] = (f32x4){0.f, 0.f, 0.f, 0.f};

  const unsigned short* Bb = Wt + (size_t)lr * NF + lh * 8;
#pragma unroll
  for (int kk = 0; kk < 4; kk++) {
    bf16x8 bfr[8];
#pragma unroll
    for (int nn = 0; nn < 8; nn++)
      bfr[nn] = *(const bf16x8*)(Bb + nn * 16 * NF + kk * 32);
#pragma unroll
    for (int m = 0; m < 2; m++)
#pragma unroll
      for (int nn = 0; nn < 8; nn++)
        acc[m][nn] = __builtin_amdgcn_mfma_f32_16x16x32_bf16(af[m][kk], bfr[nn], acc[m][nn], 0, 0, 0);
  }

  if (MODE == 0) {
    // fused s/d
    float as[8], ad[8];
#pragma unroll
    for (int nn = 0; nn < 8; nn++) {
      as[nn] = asrc[nn * 16 + lr];
      ad[nn] = adst[nn * 16 + lr];
    }
#pragma unroll
    for (int m = 0; m < 2; m++) {
#pragma unroll
      for (int r = 0; r < 4; r++) {
        int row = row0 + m * 16 + lh * 4 + r;
        float sp = 0.f, dp = 0.f;
#pragma unroll
        for (int nn = 0; nn < 8; nn++) {
          float v = acc[m][nn][r];
          sp += v * as[nn];
          dp += v * ad[nn];
          Cb[(size_t)row * NF + nn * 16 + lr] = f2bf(v);
        }
#pragma unroll
        for (int mk = 8; mk > 0; mk >>= 1) {
          sp += __shfl_xor(sp, mk);
          dp += __shfl_xor(dp, mk);
        }
        if (lr == 0) { sv[row] = sp; dv[row] = dp; }
      }
    }
  } else {
    float bcol[8];
#pragma unroll
    for (int nn = 0; nn < 8; nn++) bcol[nn] = bias[nn * 16 + lr];
#pragma unroll
    for (int m = 0; m < 2; m++)
#pragma unroll
      for (int r = 0; r < 4; r++) {
        int row = row0 + m * 16 + lh * 4 + r;
        if (row < n) {
#pragma unroll
          for (int nn = 0; nn < 8; nn++)
            Cf[(size_t)row * NF + nn * 16 + lr] = acc[m][nn][r] + bcol[nn];
        }
      }
  }
}

// ---------------- fused softmax + gather (wave per dst node) ----------------

__global__ void k_attn_gather(const float* __restrict__ sv, const float* __restrict__ dv,
                              const int* __restrict__ offs, const int* __restrict__ csr,
                              const unsigned short* __restrict__ hbf,
                              const float* __restrict__ bias, float* __restrict__ agg, int n) {
  int node = blockIdx.x * 4 + (threadIdx.x >> 6);
  int l = threadIdx.x & 63;
  if (node >= n) return;
  int o0 = offs[node], o1 = offs[node + 1];
  int deg = o1 - o0;
  float di = dv[node];
  float2 acc;
  acc.x = bias[2 * l];
  acc.y = bias[2 * l + 1];

  if (deg <= 64) {
    // one lane per edge; weights + srcs stay in registers, broadcast via shfl
    bool valid = l < deg;
    int srcj = valid ? csr[o0 + l] : 0;
    float e = valid ? sv[srcj] + di : -1e30f;
    e = e >= 0.f ? e : SLOPE * e;
    float m = e;
#pragma unroll
    for (int k = 32; k > 0; k >>= 1) m = fmaxf(m, __shfl_xor(m, k));
    float p = valid ? __expf(e - m) : 0.f;
    float z = p;
#pragma unroll
    for (int k = 32; k > 0; k >>= 1) z += __shfl_xor(z, k);
    float wj = p / z;
    int t = 0;
    for (; t + 1 < deg; t += 2) {
      int s0 = __shfl(srcj, t);
      int s1 = __shfl(srcj, t + 1);
      float w0 = __shfl(wj, t);
      float w1 = __shfl(wj, t + 1);
      unsigned int h0 = *(const unsigned int*)(hbf + (size_t)s0 * NF + 2 * l);
      unsigned int h1 = *(const unsigned int*)(hbf + (size_t)s1 * NF + 2 * l);
      acc.x += w0 * __builtin_bit_cast(float, h0 << 16) +
               w1 * __builtin_bit_cast(float, h1 << 16);
      acc.y += w0 * __builtin_bit_cast(float, h0 & 0xffff0000u) +
               w1 * __builtin_bit_cast(float, h1 & 0xffff0000u);
    }
    if (t < deg) {
      int s0 = __shfl(srcj, t);
      float w0 = __shfl(wj, t);
      unsigned int h0 = *(const unsigned int*)(hbf + (size_t)s0 * NF + 2 * l);
      acc.x += w0 * __builtin_bit_cast(float, h0 << 16);
      acc.y += w0 * __builtin_bit_cast(float, h0 & 0xffff0000u);
    }
  } else {
    // generic 3-pass path (rare)
    float m = -1e30f;
    for (int j = o0 + l; j < o1; j += 64) {
      float e = sv[csr[j]] + di;
      e = e >= 0.f ? e : SLOPE * e;
      m = fmaxf(m, e);
    }
#pragma unroll
    for (int k = 32; k > 0; k >>= 1) m = fmaxf(m, __shfl_xor(m, k));
    float z = 0.f;
    for (int j = o0 + l; j < o1; j += 64) {
      float e = sv[csr[j]] + di;
      e = e >= 0.f ? e : SLOPE * e;
      z += __expf(e - m);
    }
#pragma unroll
    for (int k = 32; k > 0; k >>= 1) z += __shfl_xor(z, k);
    float inv = 1.f / z;
    for (int j = o0; j < o1; j++) {
      int s0 = csr[j];
      float e = sv[s0] + di;
      e = e >= 0.f ? e : SLOPE * e;
      float w0 = __expf(e - m) * inv;
      unsigned int h0 = *(const unsigned int*)(hbf + (size_t)s0 * NF + 2 * l);
      acc.x += w0 * __builtin_bit_cast(float, h0 << 16);
      acc.y += w0 * __builtin_bit_cast(float, h0 & 0xffff0000u);
    }
  }
  *(float2*)&agg[(size_t)node * NF + 2 * l] = acc;
}

// ---------------- BN stats + fused finalize/apply ----------------

__global__ void k_bnstats(const float* __restrict__ x, float* __restrict__ stats, int n) {
  __shared__ float ls[256], lss[256];
  int col = threadIdx.x & 127;
  int half = threadIdx.x >> 7;
  float s = 0.f, ss = 0.f;
  for (int r = blockIdx.x * 2 + half; r < n; r += gridDim.x * 2) {
    float v = x[(size_t)r * NF + col];
    s += v;
    ss += v * v;
  }
  ls[threadIdx.x] = s;
  lss[threadIdx.x] = ss;
  __syncthreads();
  if (half == 0) {
    s += ls[col + 128];
    ss += lss[col + 128];
    atomicAdd(&stats[col], s);
    atomicAdd(&stats[NF + col], ss);
  }
}

// RELU_RES=1: hcur = relu(bn(agg)) + hcur (f32), and hb = bf16(hcur)
// RELU_RES=0: hb = bf16(bn(agg)) only
template <int RELU_RES>
__global__ void k_bn_apply(const float* __restrict__ agg, const float* __restrict__ stats,
                           const float* __restrict__ gamma, const float* __restrict__ beta,
                           float* __restrict__ hcur, unsigned short* __restrict__ hb,
                           int n, float ninv) {
  int col = threadIdx.x & 127;
  float mu = stats[col] * ninv;
  float var = stats[NF + col] * ninv - mu * mu;
  float sc = gamma[col] * rsqrtf(var + EPS);
  float sh = beta[col] - mu * sc;
  for (int r = blockIdx.x * 2 + (threadIdx.x >> 7); r < n; r += gridDim.x * 2) {
    size_t i = (size_t)r * NF + col;
    float v = agg[i] * sc + sh;
    if (RELU_RES) {
      v = fmaxf(v, 0.f) + hcur[i];
      hcur[i] = v;
    }
    hb[i] = f2bf(v);
  }
}

// ---------------- launcher ----------------

extern "C" void kernel_launch(void* const* d_in, const int* in_sizes, int n_in,
                              void* d_out, int out_size, void* d_ws, size_t ws_size,
                              hipStream_t stream) {
  (void)n_in; (void)out_size; (void)ws_size;
  const float* x     = (const float*)d_in[0];
  const int*   ei    = (const int*)d_in[1];
  const float* W0    = (const float*)d_in[2];
  const float* asrc0 = (const float*)d_in[3];
  const float* adst0 = (const float*)d_in[4];
  const float* b0    = (const float*)d_in[5];
  const float* Wm    = (const float*)d_in[6];
  const float* asrcm = (const float*)d_in[7];
  const float* adstm = (const float*)d_in[8];
  const float* bm    = (const float*)d_in[9];
  const float* W5    = (const float*)d_in[10];
  const float* asrc5 = (const float*)d_in[11];
  const float* adst5 = (const float*)d_in[12];
  const float* b5    = (const float*)d_in[13];
  const float* gammas= (const float*)d_in[14];
  const float* betas = (const float*)d_in[15];
  const float* Wr    = (const float*)d_in[16];
  const float* br    = (const float*)d_in[17];
  const float* Wo    = (const float*)d_in[18];
  const float* bo    = (const float*)d_in[19];

  const int n = in_sizes[0] / NF;
  const int np = (n + 127) & ~127;
  const int e = in_sizes[1] / 2;
  const int tot = e + n;
  const int* srcp = ei;
  const int* dstp = ei + e;

  char* w = (char*)d_ws;
  auto carve = [&](size_t bytes) {
    char* p = w;
    w += (bytes + 255) & ~(size_t)255;
    return p;
  };
  unsigned short* h_bf   = (unsigned short*)carve((size_t)np * NF * 2);
  unsigned short* hlin_bf= (unsigned short*)carve((size_t)np * NF * 2);
  unsigned short* Wt     = (unsigned short*)carve((size_t)8 * NF * NF * 2);
  float* h_cur   = (float*)carve((size_t)n * NF * 4);
  float* agg     = (float*)carve((size_t)n * NF * 4);
  float* sv      = (float*)carve((size_t)np * 4);
  float* dv      = (float*)carve((size_t)np * 4);
  int*   csr     = (int*)carve((size_t)tot * 4);
  int*   offsets = (int*)carve((size_t)(n + 1) * 4);
  int*   counts  = (int*)carve((size_t)n * 4);  // reused as cursor
  int*   partials= (int*)carve(64 * 4);
  float* stats   = (float*)carve(256 * 4);

  int nb = (n + 2047) / 2048;

  // one-time converts
  k_wt<<<(8 * NF * NF + 255) / 256, 256, 0, stream>>>(W0, Wm, W5, Wr, Wo, Wt);
  k_f32_to_bf16<<<(np * NF + 255) / 256, 256, 0, stream>>>(x, h_bf, n, np);

  // CSR build (dst-sorted; self-loop first per segment)
  k_init_counts<<<(n + 255) / 256, 256, 0, stream>>>(counts, n);
  k_count<<<(e + 255) / 256, 256, 0, stream>>>(dstp, counts, e);
  k_scan_part<<<nb, 256, 0, stream>>>(counts, partials, n);
  k_scan_mid<<<1, 64, 0, stream>>>(partials, nb);
  k_scan_final<<<nb, 256, 0, stream>>>(counts, partials, offsets, n);
  k_selfloop<<<(n + 255) / 256, 256, 0, stream>>>(offsets, counts, csr, n, tot);
  k_fill<<<(e + 255) / 256, 256, 0, stream>>>(srcp, dstp, counts, csr, e);

  int gemm_grid = np / 128;

  // residual = x @ Wr + br  (f32 out)
  k_gemm_mfma<1><<<gemm_grid, 256, 0, stream>>>(h_bf, Wt + 6 * NF * NF, nullptr, nullptr,
                                                br, nullptr, h_cur, nullptr, nullptr, n);

  for (int L = 0; L < 6; L++) {
    const float *als, *ald, *bl;
    int matIdx = L;
    if (L == 0)      { als = asrc0; ald = adst0; bl = b0; }
    else if (L <= 4) { als = asrcm + (L - 1) * NF; ald = adstm + (L - 1) * NF; bl = bm + (L - 1) * NF; }
    else             { als = asrc5; ald = adst5; bl = b5; }

    // h_lin (bf16) + fused s/d
    k_gemm_mfma<0><<<gemm_grid, 256, 0, stream>>>(h_bf, Wt + (size_t)matIdx * NF * NF,
                                                  als, ald, nullptr, hlin_bf, nullptr, sv, dv, n);
    k_attn_gather<<<(n + 3) / 4, 256, 0, stream>>>(sv, dv, offsets, csr, hlin_bf, bl, agg, n);

    hipMemsetAsync(stats, 0, 256 * 4, stream);
    k_bnstats<<<1024, 256, 0, stream>>>(agg, stats, n);

    if (L < 5) {
      k_bn_apply<1><<<1024, 256, 0, stream>>>(agg, stats, gammas + L * NF, betas + L * NF,
                                              h_cur, h_bf, n, 1.0f / n);
    } else {
      k_bn_apply<0><<<1024, 256, 0, stream>>>(agg, stats, gammas + L * NF, betas + L * NF,
                                              nullptr, hlin_bf, n, 1.0f / n);
      k_gemm_mfma<1><<<gemm_grid, 256, 0, stream>>>(hlin_bf, Wt + 7 * NF * NF, nullptr, nullptr,
                                                    bo, nullptr, (float*)d_out, nullptr, nullptr, n);
    }
  }
}

// Round 3
// 995.831 us; speedup vs baseline: 2.6783x; 1.3414x over previous
//
#include <hip/hip_runtime.h>

#define NF 128
#define EPS 1e-5f
#define SLOPE 0.2f

typedef __attribute__((ext_vector_type(8))) short bf16x8;
typedef __attribute__((ext_vector_type(4))) float f32x4;

static __device__ __forceinline__ unsigned short f2bf(float f) {
  unsigned int u = __builtin_bit_cast(unsigned int, f);
  u += 0x7fffu + ((u >> 16) & 1u);
  return (unsigned short)(u >> 16);
}
static __device__ __forceinline__ float bf2f(unsigned short s) {
  return __builtin_bit_cast(float, (unsigned int)s << 16);
}
static __device__ __forceinline__ float bflo(unsigned int u) {
  return __builtin_bit_cast(float, u << 16);
}
static __device__ __forceinline__ float bfhi(unsigned int u) {
  return __builtin_bit_cast(float, u & 0xffff0000u);
}

// ---------------- CSR build ----------------

__global__ void k_init_counts(int* counts, int n) {
  int i = blockIdx.x * 256 + threadIdx.x;
  if (i < n) counts[i] = 1;  // self-loop
}

// count + per-edge position (atomic moved here; fill becomes atomic-free)
__global__ void k_count(const int* __restrict__ dst, int* __restrict__ counts,
                        int* __restrict__ pos, int e) {
  int i = blockIdx.x * 256 + threadIdx.x;
  if (i < e) pos[i] = atomicAdd(&counts[dst[i]], 1);
}

__global__ void k_scan_part(const int* __restrict__ counts, int* __restrict__ partials, int n) {
  __shared__ int sd[256];
  int base = blockIdx.x * 2048;
  int sum = 0;
  for (int i = threadIdx.x; i < 2048; i += 256) {
    int idx = base + i;
    sum += (idx < n) ? counts[idx] : 0;
  }
  sd[threadIdx.x] = sum;
  __syncthreads();
  for (int s = 128; s > 0; s >>= 1) {
    if (threadIdx.x < s) sd[threadIdx.x] += sd[threadIdx.x + s];
    __syncthreads();
  }
  if (threadIdx.x == 0) partials[blockIdx.x] = sd[0];
}

__global__ void k_scan_mid(int* partials, int nb) {
  if (threadIdx.x == 0 && blockIdx.x == 0) {
    int acc = 0;
    for (int b = 0; b < nb; b++) { int v = partials[b]; partials[b] = acc; acc += v; }
  }
}

__global__ void k_scan_final(const int* __restrict__ counts, const int* __restrict__ partials,
                             int* __restrict__ offsets, int n) {
  __shared__ int sd[256];
  int t = threadIdx.x;
  int base = blockIdx.x * 2048;
  int local[8];
  int sum = 0;
#pragma unroll
  for (int j = 0; j < 8; j++) {
    int idx = base + t * 8 + j;
    int v = (idx < n) ? counts[idx] : 0;
    local[j] = sum;
    sum += v;
  }
  sd[t] = sum;
  __syncthreads();
  for (int st = 1; st < 256; st <<= 1) {
    int v = 0;
    if (t >= st) v = sd[t - st];
    __syncthreads();
    if (t >= st) sd[t] += v;
    __syncthreads();
  }
  int tb = partials[blockIdx.x] + (t > 0 ? sd[t - 1] : 0);
#pragma unroll
  for (int j = 0; j < 8; j++) {
    int idx = base + t * 8 + j;
    if (idx < n) offsets[idx] = tb + local[j];
  }
}

__global__ void k_selfloop(int* __restrict__ offsets, int* __restrict__ csr, int n, int total) {
  int i = blockIdx.x * 256 + threadIdx.x;
  if (i < n) csr[offsets[i]] = i;  // self-loop first (pos starts at 1)
  if (i == 0) offsets[n] = total;
}

__global__ void k_fill(const int* __restrict__ src, const int* __restrict__ dst,
                       const int* __restrict__ offsets, const int* __restrict__ pos,
                       int* __restrict__ csr, int e) {
  int i = blockIdx.x * 256 + threadIdx.x;
  if (i < e) csr[offsets[dst[i]] + pos[i]] = src[i];
}

// ---------------- converts ----------------

__global__ void k_f32_to_bf16(const float* __restrict__ x, unsigned short* __restrict__ o,
                              int n, int np) {
  int i = blockIdx.x * 256 + threadIdx.x;  // ushort4 units
  if (i >= np * (NF / 4)) return;
  int row = i >> 5;
  ushort4 ov;
  if (row < n) {
    float4 v = ((const float4*)x)[i];
    ov = make_ushort4(f2bf(v.x), f2bf(v.y), f2bf(v.z), f2bf(v.w));
  } else {
    ov = make_ushort4(0, 0, 0, 0);
  }
  ((ushort4*)o)[i] = ov;
}

__global__ void k_wt(const float* __restrict__ W0, const float* __restrict__ Wm,
                     const float* __restrict__ W5, const float* __restrict__ Wr,
                     const float* __restrict__ Wo, unsigned short* __restrict__ Wt) {
  int idx = blockIdx.x * 256 + threadIdx.x;  // 8 * 16384
  if (idx >= 8 * NF * NF) return;
  int mat = idx >> 14;
  int rem = idx & 16383;
  int r = rem >> 7;   // output col
  int k = rem & 127;  // k
  const float* W = (mat == 0) ? W0
                 : (mat <= 4) ? Wm + (size_t)(mat - 1) * NF * NF
                 : (mat == 5) ? W5
                 : (mat == 6) ? Wr : Wo;
  Wt[idx] = f2bf(W[k * NF + r]);
}

// ---------------- MFMA GEMM: C[np x 128] = A_bf16[np x 128] @ W ----------------
// MODE 0: C bf16 (unguarded, padded) + fused s/d row-dots.
// MODE 1: C f32 + bias, guarded (final output).
// MODE 2: C bf16 + bias, unguarded padded (residual init).

template <int MODE>
__global__ __launch_bounds__(256) void k_gemm_mfma(
    const unsigned short* __restrict__ A, const unsigned short* __restrict__ Wt,
    const float* __restrict__ asrc, const float* __restrict__ adst,
    const float* __restrict__ bias, unsigned short* __restrict__ Cb,
    float* __restrict__ Cf, float* __restrict__ sv, float* __restrict__ dv, int n) {
  int w = threadIdx.x >> 6;
  int l = threadIdx.x & 63;
  int lr = l & 15, lh = l >> 4;
  int row0 = blockIdx.x * 128 + w * 32;

  const unsigned short* Ab = A + (size_t)(row0 + lr) * NF + lh * 8;
  bf16x8 af[2][4];
#pragma unroll
  for (int m = 0; m < 2; m++)
#pragma unroll
    for (int kk = 0; kk < 4; kk++)
      af[m][kk] = *(const bf16x8*)(Ab + m * 16 * NF + kk * 32);

  f32x4 acc[2][8];
#pragma unroll
  for (int m = 0; m < 2; m++)
#pragma unroll
    for (int nn = 0; nn < 8; nn++) acc[m][nn] = (f32x4){0.f, 0.f, 0.f, 0.f};

  const unsigned short* Bb = Wt + (size_t)lr * NF + lh * 8;
#pragma unroll
  for (int kk = 0; kk < 4; kk++) {
    bf16x8 bfr[8];
#pragma unroll
    for (int nn = 0; nn < 8; nn++)
      bfr[nn] = *(const bf16x8*)(Bb + nn * 16 * NF + kk * 32);
#pragma unroll
    for (int m = 0; m < 2; m++)
#pragma unroll
      for (int nn = 0; nn < 8; nn++)
        acc[m][nn] = __builtin_amdgcn_mfma_f32_16x16x32_bf16(af[m][kk], bfr[nn], acc[m][nn], 0, 0, 0);
  }

  if (MODE == 0) {
    float as[8], ad[8];
#pragma unroll
    for (int nn = 0; nn < 8; nn++) {
      as[nn] = asrc[nn * 16 + lr];
      ad[nn] = adst[nn * 16 + lr];
    }
#pragma unroll
    for (int m = 0; m < 2; m++) {
#pragma unroll
      for (int r = 0; r < 4; r++) {
        int row = row0 + m * 16 + lh * 4 + r;
        float sp = 0.f, dp = 0.f;
#pragma unroll
        for (int nn = 0; nn < 8; nn++) {
          float v = acc[m][nn][r];
          sp += v * as[nn];
          dp += v * ad[nn];
          Cb[(size_t)row * NF + nn * 16 + lr] = f2bf(v);
        }
#pragma unroll
        for (int mk = 8; mk > 0; mk >>= 1) {
          sp += __shfl_xor(sp, mk);
          dp += __shfl_xor(dp, mk);
        }
        if (lr == 0) { sv[row] = sp; dv[row] = dp; }
      }
    }
  } else if (MODE == 1) {
    float bcol[8];
#pragma unroll
    for (int nn = 0; nn < 8; nn++) bcol[nn] = bias[nn * 16 + lr];
#pragma unroll
    for (int m = 0; m < 2; m++)
#pragma unroll
      for (int r = 0; r < 4; r++) {
        int row = row0 + m * 16 + lh * 4 + r;
        if (row < n) {
#pragma unroll
          for (int nn = 0; nn < 8; nn++)
            Cf[(size_t)row * NF + nn * 16 + lr] = acc[m][nn][r] + bcol[nn];
        }
      }
  } else {
    float bcol[8];
#pragma unroll
    for (int nn = 0; nn < 8; nn++) bcol[nn] = bias[nn * 16 + lr];
#pragma unroll
    for (int m = 0; m < 2; m++)
#pragma unroll
      for (int r = 0; r < 4; r++) {
        int row = row0 + m * 16 + lh * 4 + r;
#pragma unroll
        for (int nn = 0; nn < 8; nn++)
          Cb[(size_t)row * NF + nn * 16 + lr] = f2bf(acc[m][nn][r] + bcol[nn]);
      }
  }
}

// ---------------- fused softmax + gather + BN partial stats ----------------
// 256 thr = 4 waves; wave handles 4 nodes serially. Half-wave split:
// lanes 0-31 even edges, 32-63 odd edges; lane covers cols 4*ll..4*ll+3.

__global__ __launch_bounds__(256) void k_attn_gather(
    const float* __restrict__ sv, const float* __restrict__ dv,
    const int* __restrict__ offs, const int* __restrict__ csr,
    const unsigned short* __restrict__ hbf, const float* __restrict__ bias,
    unsigned short* __restrict__ aggb, float* __restrict__ pstat, int n) {
  int w = threadIdx.x >> 6, l = threadIdx.x & 63;
  int ll = l & 31, hi = l >> 5;
  int node0 = blockIdx.x * 16 + w * 4;
  float p0 = 0.f, p1 = 0.f, p2 = 0.f, p3 = 0.f;
  float q0 = 0.f, q1 = 0.f, q2 = 0.f, q3 = 0.f;
  float4 bv = *(const float4*)&bias[4 * ll];

  for (int ni = 0; ni < 4; ni++) {
    int node = node0 + ni;
    if (node >= n) break;
    int o0 = offs[node], o1 = offs[node + 1];
    int deg = o1 - o0;
    float di = dv[node];
    float a0 = 0.f, a1 = 0.f, a2 = 0.f, a3 = 0.f;

    if (deg <= 64) {
      bool valid = l < deg;
      int srcj = valid ? csr[o0 + l] : 0;
      float ev = valid ? sv[srcj] + di : -1e30f;
      ev = ev >= 0.f ? ev : SLOPE * ev;
      float m = ev;
#pragma unroll
      for (int k2 = 32; k2 > 0; k2 >>= 1) m = fmaxf(m, __shfl_xor(m, k2));
      float pe = valid ? __expf(ev - m) : 0.f;
      float z = pe;
#pragma unroll
      for (int k2 = 32; k2 > 0; k2 >>= 1) z += __shfl_xor(z, k2);
      float wj = pe / z;
      for (int t2 = 0; t2 < deg; t2 += 2) {
        int tt = t2 + hi;
        int sI = __shfl(srcj, tt & 63);
        float wI = __shfl(wj, tt & 63);
        if (tt < deg) {
          uint2 hv = *(const uint2*)(hbf + (size_t)sI * NF + 4 * ll);
          a0 += wI * bflo(hv.x);
          a1 += wI * bfhi(hv.x);
          a2 += wI * bflo(hv.y);
          a3 += wI * bfhi(hv.y);
        }
      }
    } else {
      float m = -1e30f;
      for (int j = o0 + l; j < o1; j += 64) {
        float ev = sv[csr[j]] + di;
        ev = ev >= 0.f ? ev : SLOPE * ev;
        m = fmaxf(m, ev);
      }
#pragma unroll
      for (int k2 = 32; k2 > 0; k2 >>= 1) m = fmaxf(m, __shfl_xor(m, k2));
      float z = 0.f;
      for (int j = o0 + l; j < o1; j += 64) {
        float ev = sv[csr[j]] + di;
        ev = ev >= 0.f ? ev : SLOPE * ev;
        z += __expf(ev - m);
      }
#pragma unroll
      for (int k2 = 32; k2 > 0; k2 >>= 1) z += __shfl_xor(z, k2);
      float inv = 1.f / z;
      for (int t2 = 0; t2 < deg; t2 += 2) {
        int tt = t2 + hi;
        if (tt < deg) {
          int sI = csr[o0 + tt];
          float ev = sv[sI] + di;
          ev = ev >= 0.f ? ev : SLOPE * ev;
          float wI = __expf(ev - m) * inv;
          uint2 hv = *(const uint2*)(hbf + (size_t)sI * NF + 4 * ll);
          a0 += wI * bflo(hv.x);
          a1 += wI * bfhi(hv.x);
          a2 += wI * bflo(hv.y);
          a3 += wI * bfhi(hv.y);
        }
      }
    }
    a0 += __shfl_xor(a0, 32);
    a1 += __shfl_xor(a1, 32);
    a2 += __shfl_xor(a2, 32);
    a3 += __shfl_xor(a3, 32);
    if (hi == 0) {
      a0 += bv.x; a1 += bv.y; a2 += bv.z; a3 += bv.w;
      *(ushort4*)(aggb + (size_t)node * NF + 4 * ll) =
          make_ushort4(f2bf(a0), f2bf(a1), f2bf(a2), f2bf(a3));
      p0 += a0; q0 += a0 * a0;
      p1 += a1; q1 += a1 * a1;
      p2 += a2; q2 += a2 * a2;
      p3 += a3; q3 += a3 * a3;
    }
  }

  __shared__ float red[4][32][8];
  if (hi == 0) {
    red[w][ll][0] = p0; red[w][ll][1] = p1; red[w][ll][2] = p2; red[w][ll][3] = p3;
    red[w][ll][4] = q0; red[w][ll][5] = q1; red[w][ll][6] = q2; red[w][ll][7] = q3;
  }
  __syncthreads();
  int t = threadIdx.x;
  int c = t & 127, kind = t >> 7;
  float v = red[0][c >> 2][(c & 3) + 4 * kind] + red[1][c >> 2][(c & 3) + 4 * kind] +
            red[2][c >> 2][(c & 3) + 4 * kind] + red[3][c >> 2][(c & 3) + 4 * kind];
  atomicAdd(&pstat[(blockIdx.x & 63) * 256 + t], v);
}

// ---------------- BN finalize (reduce partials -> scale/shift, re-zero) ----------------

__global__ void k_bnfinal(float* __restrict__ pstat, const float* __restrict__ gamma,
                          const float* __restrict__ beta, float* __restrict__ scsh,
                          float ninv) {
  __shared__ float tot[256];
  int t = threadIdx.x;
  float v = 0.f;
  for (int s2 = 0; s2 < 64; s2++) {
    v += pstat[s2 * 256 + t];
    pstat[s2 * 256 + t] = 0.f;
  }
  tot[t] = v;
  __syncthreads();
  if (t < 128) {
    float mu = tot[t] * ninv;
    float var = tot[128 + t] * ninv - mu * mu;
    float sc = gamma[t] * rsqrtf(var + EPS);
    scsh[t] = sc;
    scsh[128 + t] = beta[t] - mu * sc;
  }
}

// ---------------- BN apply (+relu+residual), all bf16 ----------------
// RELU_RES=1: out = bf16( relu(bn(agg)) + bf2f(res) )
// RELU_RES=0: out = bf16( bn(agg) )

template <int RELU_RES>
__global__ __launch_bounds__(256) void k_bn_apply(
    const unsigned short* __restrict__ agg, const float* __restrict__ scsh,
    const unsigned short* __restrict__ res, unsigned short* __restrict__ out, int n) {
  int cq = threadIdx.x & 31;  // ushort4 column group
  int c0 = cq * 4;
  float sc0 = scsh[c0], sc1 = scsh[c0 + 1], sc2 = scsh[c0 + 2], sc3 = scsh[c0 + 3];
  float sh0 = scsh[128 + c0], sh1 = scsh[128 + c0 + 1], sh2 = scsh[128 + c0 + 2],
        sh3 = scsh[128 + c0 + 3];
  for (int r = blockIdx.x * 8 + (threadIdx.x >> 5); r < n; r += gridDim.x * 8) {
    size_t i = (size_t)r * 32 + cq;
    ushort4 av = ((const ushort4*)agg)[i];
    float v0 = bf2f(av.x) * sc0 + sh0;
    float v1 = bf2f(av.y) * sc1 + sh1;
    float v2 = bf2f(av.z) * sc2 + sh2;
    float v3 = bf2f(av.w) * sc3 + sh3;
    if (RELU_RES) {
      ushort4 rv = ((const ushort4*)res)[i];
      v0 = fmaxf(v0, 0.f) + bf2f(rv.x);
      v1 = fmaxf(v1, 0.f) + bf2f(rv.y);
      v2 = fmaxf(v2, 0.f) + bf2f(rv.z);
      v3 = fmaxf(v3, 0.f) + bf2f(rv.w);
    }
    ((ushort4*)out)[i] = make_ushort4(f2bf(v0), f2bf(v1), f2bf(v2), f2bf(v3));
  }
}

// ---------------- launcher ----------------

extern "C" void kernel_launch(void* const* d_in, const int* in_sizes, int n_in,
                              void* d_out, int out_size, void* d_ws, size_t ws_size,
                              hipStream_t stream) {
  (void)n_in; (void)out_size; (void)ws_size;
  const float* x     = (const float*)d_in[0];
  const int*   ei    = (const int*)d_in[1];
  const float* W0    = (const float*)d_in[2];
  const float* asrc0 = (const float*)d_in[3];
  const float* adst0 = (const float*)d_in[4];
  const float* b0    = (const float*)d_in[5];
  const float* Wm    = (const float*)d_in[6];
  const float* asrcm = (const float*)d_in[7];
  const float* adstm = (const float*)d_in[8];
  const float* bm    = (const float*)d_in[9];
  const float* W5    = (const float*)d_in[10];
  const float* asrc5 = (const float*)d_in[11];
  const float* adst5 = (const float*)d_in[12];
  const float* b5    = (const float*)d_in[13];
  const float* gammas= (const float*)d_in[14];
  const float* betas = (const float*)d_in[15];
  const float* Wr    = (const float*)d_in[16];
  const float* br    = (const float*)d_in[17];
  const float* Wo    = (const float*)d_in[18];
  const float* bo    = (const float*)d_in[19];

  const int n = in_sizes[0] / NF;
  const int np = (n + 127) & ~127;
  const int e = in_sizes[1] / 2;
  const int tot = e + n;
  const int* srcp = ei;
  const int* dstp = ei + e;

  char* w = (char*)d_ws;
  auto carve = [&](size_t bytes) {
    char* p = w;
    w += (bytes + 255) & ~(size_t)255;
    return p;
  };
  unsigned short* h_bf    = (unsigned short*)carve((size_t)np * NF * 2);
  unsigned short* hlin_bf = (unsigned short*)carve((size_t)np * NF * 2);
  unsigned short* res_bf  = (unsigned short*)carve((size_t)np * NF * 2);
  unsigned short* agg_bf  = (unsigned short*)carve((size_t)n * NF * 2);
  unsigned short* Wt      = (unsigned short*)carve((size_t)8 * NF * NF * 2);
  float* sv      = (float*)carve((size_t)np * 4);
  float* dv      = (float*)carve((size_t)np * 4);
  int*   csr     = (int*)carve((size_t)tot * 4);
  int*   offsets = (int*)carve((size_t)(n + 1) * 4);
  int*   counts  = (int*)carve((size_t)n * 4);
  int*   pos     = (int*)carve((size_t)e * 4);
  int*   partials= (int*)carve(64 * 4);
  float* pstat   = (float*)carve(64 * 256 * 4);
  float* scsh    = (float*)carve(256 * 4);

  int nb = (n + 2047) / 2048;

  // one-time converts
  k_wt<<<(8 * NF * NF + 255) / 256, 256, 0, stream>>>(W0, Wm, W5, Wr, Wo, Wt);
  k_f32_to_bf16<<<(np * (NF / 4) + 255) / 256, 256, 0, stream>>>(x, h_bf, n, np);

  // CSR build
  k_init_counts<<<(n + 255) / 256, 256, 0, stream>>>(counts, n);
  k_count<<<(e + 255) / 256, 256, 0, stream>>>(dstp, counts, pos, e);
  k_scan_part<<<nb, 256, 0, stream>>>(counts, partials, n);
  k_scan_mid<<<1, 64, 0, stream>>>(partials, nb);
  k_scan_final<<<nb, 256, 0, stream>>>(counts, partials, offsets, n);
  k_selfloop<<<(n + 255) / 256, 256, 0, stream>>>(offsets, csr, n, tot);
  k_fill<<<(e + 255) / 256, 256, 0, stream>>>(srcp, dstp, offsets, pos, csr, e);

  hipMemsetAsync(pstat, 0, 64 * 256 * 4, stream);

  int gemm_grid = np / 128;

  // residual = bf16(x @ Wr + br)
  k_gemm_mfma<2><<<gemm_grid, 256, 0, stream>>>(h_bf, Wt + 6 * NF * NF, nullptr, nullptr,
                                                br, res_bf, nullptr, nullptr, nullptr, n);

  for (int L = 0; L < 6; L++) {
    const float *als, *ald, *bl;
    if (L == 0)      { als = asrc0; ald = adst0; bl = b0; }
    else if (L <= 4) { als = asrcm + (L - 1) * NF; ald = adstm + (L - 1) * NF; bl = bm + (L - 1) * NF; }
    else             { als = asrc5; ald = adst5; bl = b5; }

    k_gemm_mfma<0><<<gemm_grid, 256, 0, stream>>>(h_bf, Wt + (size_t)L * NF * NF,
                                                  als, ald, nullptr, hlin_bf, nullptr, sv, dv, n);
    k_attn_gather<<<(n + 15) / 16, 256, 0, stream>>>(sv, dv, offsets, csr, hlin_bf, bl,
                                                     agg_bf, pstat, n);
    k_bnfinal<<<1, 256, 0, stream>>>(pstat, gammas + L * NF, betas + L * NF, scsh, 1.0f / n);

    if (L < 5) {
      k_bn_apply<1><<<1024, 256, 0, stream>>>(agg_bf, scsh, (L == 0) ? res_bf : h_bf, h_bf, n);
    } else {
      k_bn_apply<0><<<1024, 256, 0, stream>>>(agg_bf, scsh, nullptr, hlin_bf, n);
      k_gemm_mfma<1><<<gemm_grid, 256, 0, stream>>>(hlin_bf, Wt + 7 * NF * NF, nullptr, nullptr,
                                                    bo, nullptr, (float*)d_out, nullptr, nullptr, n);
    }
  }
}

// Round 5
// 883.675 us; speedup vs baseline: 3.0182x; 1.1269x over previous
//
#include <hip/hip_runtime.h>

#define NF 128
#define EPS 1e-5f
#define SLOPE 0.2f

typedef __attribute__((ext_vector_type(8))) short bf16x8;
typedef __attribute__((ext_vector_type(4))) float f32x4;

static __device__ __forceinline__ unsigned short f2bf(float f) {
  unsigned int u = __builtin_bit_cast(unsigned int, f);
  u += 0x7fffu + ((u >> 16) & 1u);
  return (unsigned short)(u >> 16);
}
static __device__ __forceinline__ float bf2f(unsigned short s) {
  return __builtin_bit_cast(float, (unsigned int)s << 16);
}
static __device__ __forceinline__ float bflo(unsigned int u) {
  return __builtin_bit_cast(float, u << 16);
}
static __device__ __forceinline__ float bfhi(unsigned int u) {
  return __builtin_bit_cast(float, u & 0xffff0000u);
}
static __device__ __forceinline__ unsigned int pack2(float a, float b) {
  return (unsigned int)f2bf(a) | ((unsigned int)f2bf(b) << 16);
}

// ---------------- CSR build ----------------

__global__ void k_init_counts(int* counts, int n) {
  int i = blockIdx.x * 256 + threadIdx.x;
  if (i < n) counts[i] = 1;  // self-loop
}

__global__ void k_count(const int* __restrict__ dst, int* __restrict__ counts,
                        int* __restrict__ pos, int e) {
  int i = blockIdx.x * 256 + threadIdx.x;
  if (i < e) pos[i] = atomicAdd(&counts[dst[i]], 1);
}

__global__ void k_scan_part(const int* __restrict__ counts, int* __restrict__ partials, int n) {
  __shared__ int sd[256];
  int base = blockIdx.x * 2048;
  int sum = 0;
  for (int i = threadIdx.x; i < 2048; i += 256) {
    int idx = base + i;
    sum += (idx < n) ? counts[idx] : 0;
  }
  sd[threadIdx.x] = sum;
  __syncthreads();
  for (int s = 128; s > 0; s >>= 1) {
    if (threadIdx.x < s) sd[threadIdx.x] += sd[threadIdx.x + s];
    __syncthreads();
  }
  if (threadIdx.x == 0) partials[blockIdx.x] = sd[0];
}

__global__ void k_scan_mid(int* partials, int nb) {
  if (threadIdx.x == 0 && blockIdx.x == 0) {
    int acc = 0;
    for (int b = 0; b < nb; b++) { int v = partials[b]; partials[b] = acc; acc += v; }
  }
}

__global__ void k_scan_final(const int* __restrict__ counts, const int* __restrict__ partials,
                             int* __restrict__ offsets, int n) {
  __shared__ int sd[256];
  int t = threadIdx.x;
  int base = blockIdx.x * 2048;
  int local[8];
  int sum = 0;
#pragma unroll
  for (int j = 0; j < 8; j++) {
    int idx = base + t * 8 + j;
    int v = (idx < n) ? counts[idx] : 0;
    local[j] = sum;
    sum += v;
  }
  sd[t] = sum;
  __syncthreads();
  for (int st = 1; st < 256; st <<= 1) {
    int v = 0;
    if (t >= st) v = sd[t - st];
    __syncthreads();
    if (t >= st) sd[t] += v;
    __syncthreads();
  }
  int tb = partials[blockIdx.x] + (t > 0 ? sd[t - 1] : 0);
#pragma unroll
  for (int j = 0; j < 8; j++) {
    int idx = base + t * 8 + j;
    if (idx < n) offsets[idx] = tb + local[j];
  }
}

__global__ void k_selfloop(int* __restrict__ offsets, int* __restrict__ csr, int n, int total) {
  int i = blockIdx.x * 256 + threadIdx.x;
  if (i < n) csr[offsets[i]] = i;  // self-loop first (pos starts at 1)
  if (i == 0) offsets[n] = total;
}

__global__ void k_fill(const int* __restrict__ src, const int* __restrict__ dst,
                       const int* __restrict__ offsets, const int* __restrict__ pos,
                       int* __restrict__ csr, int e) {
  int i = blockIdx.x * 256 + threadIdx.x;
  if (i < e) csr[offsets[dst[i]] + pos[i]] = src[i];
}

// ---------------- converts ----------------

__global__ void k_f32_to_bf16(const float* __restrict__ x, unsigned short* __restrict__ o,
                              int n, int np) {
  int i = blockIdx.x * 256 + threadIdx.x;  // ushort4 units
  if (i >= np * (NF / 4)) return;
  int row = i >> 5;
  ushort4 ov;
  if (row < n) {
    float4 v = ((const float4*)x)[i];
    ov = make_ushort4(f2bf(v.x), f2bf(v.y), f2bf(v.z), f2bf(v.w));
  } else {
    ov = make_ushort4(0, 0, 0, 0);
  }
  ((ushort4*)o)[i] = ov;
}

__global__ void k_wt(const float* __restrict__ W0, const float* __restrict__ Wm,
                     const float* __restrict__ W5, const float* __restrict__ Wr,
                     const float* __restrict__ Wo, unsigned short* __restrict__ Wt) {
  int idx = blockIdx.x * 256 + threadIdx.x;  // 8 * 16384
  if (idx >= 8 * NF * NF) return;
  int mat = idx >> 14;
  int rem = idx & 16383;
  int r = rem >> 7;   // output col
  int k = rem & 127;  // k
  const float* W = (mat == 0) ? W0
                 : (mat <= 4) ? Wm + (size_t)(mat - 1) * NF * NF
                 : (mat == 5) ? W5
                 : (mat == 6) ? Wr : Wo;
  Wt[idx] = f2bf(W[k * NF + r]);
}

// ---------------- MFMA GEMM ----------------

template <int MODE>
__global__ __launch_bounds__(256) void k_gemm_mfma(
    const unsigned short* __restrict__ A, const unsigned short* __restrict__ Wt,
    const float* __restrict__ asrc, const float* __restrict__ adst,
    const float* __restrict__ bias, unsigned short* __restrict__ Cb,
    float* __restrict__ Cf, float* __restrict__ sv, float* __restrict__ dv, int n) {
  int w = threadIdx.x >> 6;
  int l = threadIdx.x & 63;
  int lr = l & 15, lh = l >> 4;
  int row0 = blockIdx.x * 128 + w * 32;

  const unsigned short* Ab = A + (size_t)(row0 + lr) * NF + lh * 8;
  bf16x8 af[2][4];
#pragma unroll
  for (int m = 0; m < 2; m++)
#pragma unroll
    for (int kk = 0; kk < 4; kk++)
      af[m][kk] = *(const bf16x8*)(Ab + m * 16 * NF + kk * 32);

  f32x4 acc[2][8];
#pragma unroll
  for (int m = 0; m < 2; m++)
#pragma unroll
    for (int nn = 0; nn < 8; nn++) acc[m][nn] = (f32x4){0.f, 0.f, 0.f, 0.f};

  const unsigned short* Bb = Wt + (size_t)lr * NF + lh * 8;
#pragma unroll
  for (int kk = 0; kk < 4; kk++) {
    bf16x8 bfr[8];
#pragma unroll
    for (int nn = 0; nn < 8; nn++)
      bfr[nn] = *(const bf16x8*)(Bb + nn * 16 * NF + kk * 32);
#pragma unroll
    for (int m = 0; m < 2; m++)
#pragma unroll
      for (int nn = 0; nn < 8; nn++)
        acc[m][nn] = __builtin_amdgcn_mfma_f32_16x16x32_bf16(af[m][kk], bfr[nn], acc[m][nn], 0, 0, 0);
  }

  if (MODE == 0) {
    float as[8], ad[8];
#pragma unroll
    for (int nn = 0; nn < 8; nn++) {
      as[nn] = asrc[nn * 16 + lr];
      ad[nn] = adst[nn * 16 + lr];
    }
#pragma unroll
    for (int m = 0; m < 2; m++) {
#pragma unroll
      for (int r = 0; r < 4; r++) {
        int row = row0 + m * 16 + lh * 4 + r;
        float sp = 0.f, dp = 0.f;
#pragma unroll
        for (int nn = 0; nn < 8; nn++) {
          float v = acc[m][nn][r];
          sp += v * as[nn];
          dp += v * ad[nn];
          Cb[(size_t)row * NF + nn * 16 + lr] = f2bf(v);
        }
#pragma unroll
        for (int mk = 8; mk > 0; mk >>= 1) {
          sp += __shfl_xor(sp, mk);
          dp += __shfl_xor(dp, mk);
        }
        if (lr == 0) { sv[row] = sp; dv[row] = dp; }
      }
    }
  } else if (MODE == 1) {
    float bcol[8];
#pragma unroll
    for (int nn = 0; nn < 8; nn++) bcol[nn] = bias[nn * 16 + lr];
#pragma unroll
    for (int m = 0; m < 2; m++)
#pragma unroll
      for (int r = 0; r < 4; r++) {
        int row = row0 + m * 16 + lh * 4 + r;
        if (row < n) {
#pragma unroll
          for (int nn = 0; nn < 8; nn++)
            Cf[(size_t)row * NF + nn * 16 + lr] = acc[m][nn][r] + bcol[nn];
        }
      }
  } else {
    float bcol[8];
#pragma unroll
    for (int nn = 0; nn < 8; nn++) bcol[nn] = bias[nn * 16 + lr];
#pragma unroll
    for (int m = 0; m < 2; m++)
#pragma unroll
      for (int r = 0; r < 4; r++) {
        int row = row0 + m * 16 + lh * 4 + r;
#pragma unroll
        for (int nn = 0; nn < 8; nn++)
          Cb[(size_t)row * NF + nn * 16 + lr] = f2bf(acc[m][nn][r] + bcol[nn]);
      }
  }
}

// ---------------- fused softmax + gather + BN partial stats ----------------
// 256 thr = 4 waves; wave handles 4 nodes serially.
// 4 groups of 16 lanes; lane covers 8 cols (uint4 = 16B). 2 loads unrolled
// per iter -> 8 edges in flight per wave.
// NOTE: all __shfl are UNCONDITIONAL (wave fully active) — lanes l >= deg
// carry wj == 0, so out-of-range edges self-nullify. Shfl inside divergent
// code is UB on CDNA (round-4 failure).

__global__ __launch_bounds__(256) void k_attn_gather(
    const float* __restrict__ sv, const float* __restrict__ dv,
    const int* __restrict__ offs, const int* __restrict__ csr,
    const unsigned short* __restrict__ hbf, const float* __restrict__ bias,
    unsigned short* __restrict__ aggb, float* __restrict__ pstat, int n) {
  int w = threadIdx.x >> 6, l = threadIdx.x & 63;
  int ll = l & 15, g = l >> 4;
  int node0 = blockIdx.x * 16 + w * 4;
  float ps[8] = {0.f, 0.f, 0.f, 0.f, 0.f, 0.f, 0.f, 0.f};
  float qs[8] = {0.f, 0.f, 0.f, 0.f, 0.f, 0.f, 0.f, 0.f};
  float4 bv0 = *(const float4*)&bias[8 * ll];
  float4 bv1 = *(const float4*)&bias[8 * ll + 4];

  for (int ni = 0; ni < 4; ni++) {
    int node = node0 + ni;
    if (node >= n) break;
    int o0 = offs[node], o1 = offs[node + 1];
    int deg = o1 - o0;
    float di = dv[node];
    float a[8] = {0.f, 0.f, 0.f, 0.f, 0.f, 0.f, 0.f, 0.f};

    if (deg <= 64) {
      bool valid = l < deg;
      int srcj = valid ? csr[o0 + l] : 0;
      float ev = valid ? sv[srcj] + di : -1e30f;
      ev = ev >= 0.f ? ev : SLOPE * ev;
      float m = ev;
#pragma unroll
      for (int k2 = 32; k2 > 0; k2 >>= 1) m = fmaxf(m, __shfl_xor(m, k2));
      float pe = valid ? __expf(ev - m) : 0.f;
      float z = pe;
#pragma unroll
      for (int k2 = 32; k2 > 0; k2 >>= 1) z += __shfl_xor(z, k2);
      float wj = pe / z;  // == 0 for lanes l >= deg

      for (int t2 = 0; t2 < deg; t2 += 8) {
        int ta = t2 + g;        // <= 59, no wrap
        int tb = t2 + 4 + g;    // <= 63, no wrap
        int sA = __shfl(srcj, ta);       // unconditional: full wave active
        int sB = __shfl(srcj, tb);
        float wA = __shfl(wj, ta);       // wj==0 beyond deg -> auto-null
        float wB = __shfl(wj, tb);
        uint4 hA = *(const uint4*)(hbf + (size_t)sA * NF + 8 * ll);
        uint4 hB = *(const uint4*)(hbf + (size_t)sB * NF + 8 * ll);
        a[0] += wA * bflo(hA.x) + wB * bflo(hB.x);
        a[1] += wA * bfhi(hA.x) + wB * bfhi(hB.x);
        a[2] += wA * bflo(hA.y) + wB * bflo(hB.y);
        a[3] += wA * bfhi(hA.y) + wB * bfhi(hB.y);
        a[4] += wA * bflo(hA.z) + wB * bflo(hB.z);
        a[5] += wA * bfhi(hA.z) + wB * bfhi(hB.z);
        a[6] += wA * bflo(hA.w) + wB * bflo(hB.w);
        a[7] += wA * bfhi(hA.w) + wB * bfhi(hB.w);
      }
    } else {
      float m = -1e30f;
      for (int j = o0 + l; j < o1; j += 64) {
        float ev = sv[csr[j]] + di;
        ev = ev >= 0.f ? ev : SLOPE * ev;
        m = fmaxf(m, ev);
      }
#pragma unroll
      for (int k2 = 32; k2 > 0; k2 >>= 1) m = fmaxf(m, __shfl_xor(m, k2));
      float z = 0.f;
      for (int j = o0 + l; j < o1; j += 64) {
        float ev = sv[csr[j]] + di;
        ev = ev >= 0.f ? ev : SLOPE * ev;
        z += __expf(ev - m);
      }
#pragma unroll
      for (int k2 = 32; k2 > 0; k2 >>= 1) z += __shfl_xor(z, k2);
      float inv = 1.f / z;
      for (int t2 = 0; t2 < deg; t2 += 4) {
        int tt = t2 + g;
        if (tt < deg) {  // divergent, but contains no shfl -> safe
          int sI = csr[o0 + tt];
          float ev = sv[sI] + di;
          ev = ev >= 0.f ? ev : SLOPE * ev;
          float wI = __expf(ev - m) * inv;
          uint4 hv = *(const uint4*)(hbf + (size_t)sI * NF + 8 * ll);
          a[0] += wI * bflo(hv.x);
          a[1] += wI * bfhi(hv.x);
          a[2] += wI * bflo(hv.y);
          a[3] += wI * bfhi(hv.y);
          a[4] += wI * bflo(hv.z);
          a[5] += wI * bfhi(hv.z);
          a[6] += wI * bflo(hv.w);
          a[7] += wI * bfhi(hv.w);
        }
      }
    }
#pragma unroll
    for (int j = 0; j < 8; j++) {
      a[j] += __shfl_xor(a[j], 16);
      a[j] += __shfl_xor(a[j], 32);
    }
    if (g == 0) {
      a[0] += bv0.x; a[1] += bv0.y; a[2] += bv0.z; a[3] += bv0.w;
      a[4] += bv1.x; a[5] += bv1.y; a[6] += bv1.z; a[7] += bv1.w;
      uint4 ov;
      ov.x = pack2(a[0], a[1]);
      ov.y = pack2(a[2], a[3]);
      ov.z = pack2(a[4], a[5]);
      ov.w = pack2(a[6], a[7]);
      *(uint4*)(aggb + (size_t)node * NF + 8 * ll) = ov;
#pragma unroll
      for (int j = 0; j < 8; j++) { ps[j] += a[j]; qs[j] += a[j] * a[j]; }
    }
  }

  __shared__ float red[4][16][17];
  if (g == 0) {
#pragma unroll
    for (int j = 0; j < 8; j++) {
      red[w][ll][j] = ps[j];
      red[w][ll][8 + j] = qs[j];
    }
  }
  __syncthreads();
  int t = threadIdx.x;
  int c = t & 127, kind = t >> 7;
  int li = c >> 3, sj = (c & 7) + 8 * kind;
  float v = red[0][li][sj] + red[1][li][sj] + red[2][li][sj] + red[3][li][sj];
  atomicAdd(&pstat[(blockIdx.x & 63) * 256 + t], v);
}

// ---------------- BN finalize ----------------

__global__ void k_bnfinal(float* __restrict__ pstat, const float* __restrict__ gamma,
                          const float* __restrict__ beta, float* __restrict__ scsh,
                          float ninv) {
  __shared__ float tot[256];
  int t = threadIdx.x;
  float v = 0.f;
  for (int s2 = 0; s2 < 64; s2++) {
    v += pstat[s2 * 256 + t];
    pstat[s2 * 256 + t] = 0.f;
  }
  tot[t] = v;
  __syncthreads();
  if (t < 128) {
    float mu = tot[t] * ninv;
    float var = tot[128 + t] * ninv - mu * mu;
    float sc = gamma[t] * rsqrtf(var + EPS);
    scsh[t] = sc;
    scsh[128 + t] = beta[t] - mu * sc;
  }
}

// ---------------- BN apply (+relu+residual), all bf16 ----------------

template <int RELU_RES>
__global__ __launch_bounds__(256) void k_bn_apply(
    const unsigned short* __restrict__ agg, const float* __restrict__ scsh,
    const unsigned short* __restrict__ res, unsigned short* __restrict__ out, int n) {
  int cq = threadIdx.x & 31;
  int c0 = cq * 4;
  float sc0 = scsh[c0], sc1 = scsh[c0 + 1], sc2 = scsh[c0 + 2], sc3 = scsh[c0 + 3];
  float sh0 = scsh[128 + c0], sh1 = scsh[128 + c0 + 1], sh2 = scsh[128 + c0 + 2],
        sh3 = scsh[128 + c0 + 3];
  for (int r = blockIdx.x * 8 + (threadIdx.x >> 5); r < n; r += gridDim.x * 8) {
    size_t i = (size_t)r * 32 + cq;
    ushort4 av = ((const ushort4*)agg)[i];
    float v0 = bf2f(av.x) * sc0 + sh0;
    float v1 = bf2f(av.y) * sc1 + sh1;
    float v2 = bf2f(av.z) * sc2 + sh2;
    float v3 = bf2f(av.w) * sc3 + sh3;
    if (RELU_RES) {
      ushort4 rv = ((const ushort4*)res)[i];
      v0 = fmaxf(v0, 0.f) + bf2f(rv.x);
      v1 = fmaxf(v1, 0.f) + bf2f(rv.y);
      v2 = fmaxf(v2, 0.f) + bf2f(rv.z);
      v3 = fmaxf(v3, 0.f) + bf2f(rv.w);
    }
    ((ushort4*)out)[i] = make_ushort4(f2bf(v0), f2bf(v1), f2bf(v2), f2bf(v3));
  }
}

// ---------------- launcher ----------------

extern "C" void kernel_launch(void* const* d_in, const int* in_sizes, int n_in,
                              void* d_out, int out_size, void* d_ws, size_t ws_size,
                              hipStream_t stream) {
  (void)n_in; (void)out_size; (void)ws_size;
  const float* x     = (const float*)d_in[0];
  const int*   ei    = (const int*)d_in[1];
  const float* W0    = (const float*)d_in[2];
  const float* asrc0 = (const float*)d_in[3];
  const float* adst0 = (const float*)d_in[4];
  const float* b0    = (const float*)d_in[5];
  const float* Wm    = (const float*)d_in[6];
  const float* asrcm = (const float*)d_in[7];
  const float* adstm = (const float*)d_in[8];
  const float* bm    = (const float*)d_in[9];
  const float* W5    = (const float*)d_in[10];
  const float* asrc5 = (const float*)d_in[11];
  const float* adst5 = (const float*)d_in[12];
  const float* b5    = (const float*)d_in[13];
  const float* gammas= (const float*)d_in[14];
  const float* betas = (const float*)d_in[15];
  const float* Wr    = (const float*)d_in[16];
  const float* br    = (const float*)d_in[17];
  const float* Wo    = (const float*)d_in[18];
  const float* bo    = (const float*)d_in[19];

  const int n = in_sizes[0] / NF;
  const int np = (n + 127) & ~127;
  const int e = in_sizes[1] / 2;
  const int tot = e + n;
  const int* srcp = ei;
  const int* dstp = ei + e;

  char* w = (char*)d_ws;
  auto carve = [&](size_t bytes) {
    char* p = w;
    w += (bytes + 255) & ~(size_t)255;
    return p;
  };
  unsigned short* h_bf    = (unsigned short*)carve((size_t)np * NF * 2);
  unsigned short* hlin_bf = (unsigned short*)carve((size_t)np * NF * 2);
  unsigned short* res_bf  = (unsigned short*)carve((size_t)np * NF * 2);
  unsigned short* agg_bf  = (unsigned short*)carve((size_t)n * NF * 2);
  unsigned short* Wt      = (unsigned short*)carve((size_t)8 * NF * NF * 2);
  float* sv      = (float*)carve((size_t)np * 4);
  float* dv      = (float*)carve((size_t)np * 4);
  int*   csr     = (int*)carve((size_t)tot * 4);
  int*   offsets = (int*)carve((size_t)(n + 1) * 4);
  int*   counts  = (int*)carve((size_t)n * 4);
  int*   pos     = (int*)carve((size_t)e * 4);
  int*   partials= (int*)carve(64 * 4);
  float* pstat   = (float*)carve(64 * 256 * 4);
  float* scsh    = (float*)carve(256 * 4);

  int nb = (n + 2047) / 2048;

  // one-time converts
  k_wt<<<(8 * NF * NF + 255) / 256, 256, 0, stream>>>(W0, Wm, W5, Wr, Wo, Wt);
  k_f32_to_bf16<<<(np * (NF / 4) + 255) / 256, 256, 0, stream>>>(x, h_bf, n, np);

  // CSR build
  k_init_counts<<<(n + 255) / 256, 256, 0, stream>>>(counts, n);
  k_count<<<(e + 255) / 256, 256, 0, stream>>>(dstp, counts, pos, e);
  k_scan_part<<<nb, 256, 0, stream>>>(counts, partials, n);
  k_scan_mid<<<1, 64, 0, stream>>>(partials, nb);
  k_scan_final<<<nb, 256, 0, stream>>>(counts, partials, offsets, n);
  k_selfloop<<<(n + 255) / 256, 256, 0, stream>>>(offsets, csr, n, tot);
  k_fill<<<(e + 255) / 256, 256, 0, stream>>>(srcp, dstp, offsets, pos, csr, e);

  hipMemsetAsync(pstat, 0, 64 * 256 * 4, stream);

  int gemm_grid = np / 128;

  // residual = bf16(x @ Wr + br)
  k_gemm_mfma<2><<<gemm_grid, 256, 0, stream>>>(h_bf, Wt + 6 * NF * NF, nullptr, nullptr,
                                                br, res_bf, nullptr, nullptr, nullptr, n);

  for (int L = 0; L < 6; L++) {
    const float *als, *ald, *bl;
    if (L == 0)      { als = asrc0; ald = adst0; bl = b0; }
    else if (L <= 4) { als = asrcm + (L - 1) * NF; ald = adstm + (L - 1) * NF; bl = bm + (L - 1) * NF; }
    else             { als = asrc5; ald = adst5; bl = b5; }

    k_gemm_mfma<0><<<gemm_grid, 256, 0, stream>>>(h_bf, Wt + (size_t)L * NF * NF,
                                                  als, ald, nullptr, hlin_bf, nullptr, sv, dv, n);
    k_attn_gather<<<(n + 15) / 16, 256, 0, stream>>>(sv, dv, offsets, csr, hlin_bf, bl,
                                                     agg_bf, pstat, n);
    k_bnfinal<<<1, 256, 0, stream>>>(pstat, gammas + L * NF, betas + L * NF, scsh, 1.0f / n);

    if (L < 5) {
      k_bn_apply<1><<<1024, 256, 0, stream>>>(agg_bf, scsh, (L == 0) ? res_bf : h_bf, h_bf, n);
    } else {
      k_bn_apply<0><<<1024, 256, 0, stream>>>(agg_bf, scsh, nullptr, hlin_bf, n);
      k_gemm_mfma<1><<<gemm_grid, 256, 0, stream>>>(hlin_bf, Wt + 7 * NF * NF, nullptr, nullptr,
                                                    bo, nullptr, (float*)d_out, nullptr, nullptr, n);
    }
  }
}